// Round 14
// baseline (4289.606 us; speedup 1.0000x reference)
//
#include <hip/hip_runtime.h>

#define L_DIM 1024
#define B_DIM 128
#define I_DIM 256
#define H_DIM 512

typedef unsigned short u16x8 __attribute__((ext_vector_type(8)));
typedef __bf16 bf16x8 __attribute__((ext_vector_type(8)));
typedef float f32x4 __attribute__((ext_vector_type(4)));
typedef unsigned long long u64;
typedef unsigned int u32;
typedef u64 u64x2 __attribute__((ext_vector_type(2)));

static __device__ __forceinline__ unsigned short f2bf(float f) {
  unsigned u = __builtin_bit_cast(unsigned, f);
  u += 0x7FFFu + ((u >> 16) & 1u);
  return (unsigned short)(u >> 16);
}
static __device__ __forceinline__ float bf2f(unsigned short b) {
  return __builtin_bit_cast(float, ((unsigned)b) << 16);
}
static __device__ __forceinline__ bf16x8 ld_frag_g(const unsigned short* p, size_t idx8) {
  return __builtin_bit_cast(bf16x8, reinterpret_cast<const u16x8*>(p)[idx8]);
}

// ---------------------------------------------------------------------------
// Pack Wx and Wh into MFMA B-fragment order, split hi/lo bf16. (unchanged)
// NOTE: WxHi/WxLo region doubles as the rnn exchange slab; pack_weights
// rewriting it EVERY launch destroys stale stamps across graph replays
// (R10-proven). Do not reorder or skip.
// ---------------------------------------------------------------------------
__global__ void pack_weights(const float* __restrict__ Wx, const float* __restrict__ Wh,
                             unsigned short* __restrict__ WxHi, unsigned short* __restrict__ WxLo,
                             unsigned short* __restrict__ WhHi, unsigned short* __restrict__ WhLo) {
  int tid = blockIdx.x * blockDim.x + threadIdx.x;
  if (tid < 32 * 8 * 64) {
    int lane = tid & 63, kt = (tid >> 6) & 7, nt = tid >> 9;
    int n = nt * 16 + (lane & 15), k0 = kt * 32 + (lane >> 4) * 8;
    const float* src = Wx + (size_t)n * I_DIM + k0;
    #pragma unroll
    for (int j = 0; j < 8; ++j) {
      float v = src[j];
      unsigned short hb = f2bf(v);
      WxHi[(size_t)tid * 8 + j] = hb;
      WxLo[(size_t)tid * 8 + j] = f2bf(v - bf2f(hb));
    }
  }
  if (tid < 32 * 16 * 64) {
    int lane = tid & 63, kt = (tid >> 6) & 15, nt = tid >> 10;
    int n = nt * 16 + (lane & 15), k0 = kt * 32 + (lane >> 4) * 8;
    const float* src = Wh + (size_t)n * H_DIM + k0;
    #pragma unroll
    for (int j = 0; j < 8; ++j) {
      float v = src[j];
      unsigned short hb = f2bf(v);
      WhHi[(size_t)tid * 8 + j] = hb;
      WhLo[(size_t)tid * 8 + j] = f2bf(v - bf2f(hb));
    }
  }
}

// ---------------------------------------------------------------------------
// xproj (unchanged)
// ---------------------------------------------------------------------------
__global__ __launch_bounds__(256) void xproj_kernel(const float* __restrict__ x,
    const unsigned short* __restrict__ WxHi, const unsigned short* __restrict__ WxLo,
    const float* __restrict__ bh, float* __restrict__ out) {
  __shared__ unsigned short ahi[128][40];
  __shared__ unsigned short alo[128][40];
  const int tid = threadIdx.x, lane = tid & 63, wid = tid >> 6;
  const int mbase = blockIdx.x * 128, cbase = blockIdx.y * 128;
  const int wrow = (wid >> 1) * 64, wcol = (wid & 1) * 64;
  f32x4 acc[4][4] = {};
  const int srow = tid >> 1, shalf = (tid & 1) * 16;

  for (int kt = 0; kt < 8; ++kt) {
    const f32x4* src = reinterpret_cast<const f32x4*>(
        x + (size_t)(mbase + srow) * I_DIM + kt * 32 + shalf);
    f32x4 v[4];
    v[0] = src[0]; v[1] = src[1]; v[2] = src[2]; v[3] = src[3];
    u16x8 hh[2], ll[2];
    #pragma unroll
    for (int q = 0; q < 2; ++q) {
      #pragma unroll
      for (int e = 0; e < 8; ++e) {
        float f = v[q * 2 + (e >> 2)][e & 3];
        unsigned short hb = f2bf(f);
        hh[q][e] = hb;
        ll[q][e] = f2bf(f - bf2f(hb));
      }
    }
    __syncthreads();
    *reinterpret_cast<u16x8*>(&ahi[srow][shalf]) = hh[0];
    *reinterpret_cast<u16x8*>(&ahi[srow][shalf + 8]) = hh[1];
    *reinterpret_cast<u16x8*>(&alo[srow][shalf]) = ll[0];
    *reinterpret_cast<u16x8*>(&alo[srow][shalf + 8]) = ll[1];
    __syncthreads();

    bf16x8 amh[4], aml[4];
    #pragma unroll
    for (int m = 0; m < 4; ++m) {
      amh[m] = __builtin_bit_cast(bf16x8, *reinterpret_cast<const u16x8*>(
          &ahi[wrow + m * 16 + (lane & 15)][(lane >> 4) * 8]));
      aml[m] = __builtin_bit_cast(bf16x8, *reinterpret_cast<const u16x8*>(
          &alo[wrow + m * 16 + (lane & 15)][(lane >> 4) * 8]));
    }
    bf16x8 bhh[4], bll[4];
    #pragma unroll
    for (int n = 0; n < 4; ++n) {
      int ntg = (cbase + wcol) / 16 + n;
      size_t idx = (size_t)(ntg * 8 + kt) * 64 + lane;
      bhh[n] = ld_frag_g(WxHi, idx);
      bll[n] = ld_frag_g(WxLo, idx);
    }
    #pragma unroll
    for (int m = 0; m < 4; ++m) {
      #pragma unroll
      for (int n = 0; n < 4; ++n) {
        acc[m][n] = __builtin_amdgcn_mfma_f32_16x16x32_bf16(amh[m], bhh[n], acc[m][n], 0, 0, 0);
        acc[m][n] = __builtin_amdgcn_mfma_f32_16x16x32_bf16(aml[m], bhh[n], acc[m][n], 0, 0, 0);
        acc[m][n] = __builtin_amdgcn_mfma_f32_16x16x32_bf16(amh[m], bll[n], acc[m][n], 0, 0, 0);
      }
    }
  }

  #pragma unroll
  for (int n = 0; n < 4; ++n) {
    int col = cbase + wcol + n * 16 + (lane & 15);
    float bv = bh[col];
    #pragma unroll
    for (int m = 0; m < 4; ++m) {
      int rg = mbase + wrow + m * 16 + ((lane >> 4) << 2);
      #pragma unroll
      for (int r = 0; r < 4; ++r)
        out[(size_t)(rg + r) * H_DIM + col] = acc[m][n][r] + bv;
    }
  }
}

// ---------------------------------------------------------------------------
// Recurrence: 64 WGs x 256 thr (4 waves). g=blk&7 (16 batch rows), c=blk>>3;
// wave w owns cols (c*4+w)*16..+15. Wh hi/lo fragments VGPR-resident
// (R4-proven; R13's global reload was a 2k cy/step regression). h_t in
// double-buffered LDS (one s_barrier/step). Exchange, ALL relaxed AGENT ops:
//   producer: 4 STAMPED u32 stores ((step<<16)|bf16 — atomic word carries
//             data+version, R10-proven) -> fetch_add(+1) on the single
//             (buf,g) counter. NO vmcnt ack — the stamp is the correctness
//             net; the counter-full observation (~2 RTT later) makes
//             round-1 freshness near-certain.
//   consumer: out stores + xp(t+2) fly; poll ONE counter word for monotonic
//             target 32*ceil(step/2); pull 16 u64 (128 B/thread, WG-dedup),
//             validate stamps (OR-tree), rare whole-batch retry; strip;
//             4x b128 scatter; lgkmcnt; s_barrier.
// Overwrite safety: counter(s+1) full => every wave consumed step s of that
// buffer => s+2 publish can't race readers. Replay safety: slab aliases the
// Wx pack region, rewritten by pack_weights every launch.
// ---------------------------------------------------------------------------
__global__ __launch_bounds__(256, 1) void rnn_kernel(const float* __restrict__ h0,
    const unsigned short* __restrict__ WhHi, const unsigned short* __restrict__ WhLo,
    u32* __restrict__ ctr, u32* __restrict__ slab,
    float* __restrict__ out) {
  __shared__ __attribute__((aligned(16))) unsigned short hb[2][16 * 520];
  const int tid = threadIdx.x, lane = tid & 63, w = tid >> 6;
  const int g = blockIdx.x & 7, c = blockIdx.x >> 3;
  const int cw = c * 4 + w;  // producer-wave index within group (0..31)

  const int arow = lane & 15;        // A row (batch); D col within 16
  const int aoff = (lane >> 4) * 8;  // A k offset (elements)
  const int drow = (lane >> 4) * 4;  // D row base
  const int gcol = cw * 16 + (lane & 15);
  const int prow = tid & 15;         // pull/scatter row
  const int pch  = tid >> 4;         // pull/scatter 32-elem chunk

  // ---- one-time: Wh fragments -> VGPRs (16 cols x 512 k, hi+lo) ----
  bf16x8 wfh[16], wfl[16];
  #pragma unroll
  for (int kt = 0; kt < 16; ++kt) {
    size_t idx = (size_t)(cw * 16 + kt) * 64 + lane;
    wfh[kt] = ld_frag_g(WhHi, idx);
    wfl[kt] = ld_frag_g(WhLo, idx);
  }

  // ---- one-time: h0 -> hb[0] (fp32 -> bf16), 32 elems/thread ----
  {
    const float* src = h0 + (size_t)(g * 16 + prow) * H_DIM + pch * 32;
    #pragma unroll
    for (int q = 0; q < 4; ++q) {
      f32x4 v0 = reinterpret_cast<const f32x4*>(src)[2 * q];
      f32x4 v1 = reinterpret_cast<const f32x4*>(src)[2 * q + 1];
      u16x8 hv;
      #pragma unroll
      for (int e = 0; e < 4; ++e) { hv[e] = f2bf(v0[e]); hv[4 + e] = f2bf(v1[e]); }
      *reinterpret_cast<u16x8*>(&hb[0][prow * 520 + pch * 32 + q * 8]) = hv;
    }
  }
  __syncthreads();

  // ---- xp pipeline depth 2 ----
  f32x4 xpA, xpB;
  #pragma unroll
  for (int r = 0; r < 4; ++r)
    xpA[r] = out[(size_t)(g * 16 + drow + r) * H_DIM + gcol];
  #pragma unroll
  for (int r = 0; r < 4; ++r)
    xpB[r] = out[(size_t)B_DIM * H_DIM + (size_t)(g * 16 + drow + r) * H_DIM + gcol];

  for (int t = 0; t < L_DIM; ++t) {
    const size_t obase = ((size_t)t * B_DIM + g * 16) * H_DIM;
    const int cur = t & 1;

    // ---- A-frags from LDS; z = h_t . Wh (hi+lo): 32 MFMAs, 4 chains ----
    f32x4 a0 = {}, a1 = {}, a2 = {}, a3 = {};
    #pragma unroll
    for (int kt = 0; kt < 16; kt += 2) {
      bf16x8 af0 = __builtin_bit_cast(bf16x8, *reinterpret_cast<const u16x8*>(
          &hb[cur][arow * 520 + kt * 32 + aoff]));
      bf16x8 af1 = __builtin_bit_cast(bf16x8, *reinterpret_cast<const u16x8*>(
          &hb[cur][arow * 520 + (kt + 1) * 32 + aoff]));
      a0 = __builtin_amdgcn_mfma_f32_16x16x32_bf16(af0, wfh[kt], a0, 0, 0, 0);
      a1 = __builtin_amdgcn_mfma_f32_16x16x32_bf16(af0, wfl[kt], a1, 0, 0, 0);
      a2 = __builtin_amdgcn_mfma_f32_16x16x32_bf16(af1, wfh[kt + 1], a2, 0, 0, 0);
      a3 = __builtin_amdgcn_mfma_f32_16x16x32_bf16(af1, wfl[kt + 1], a3, 0, 0, 0);
    }

    float hv[4]; unsigned short hu[4];
    #pragma unroll
    for (int r = 0; r < 4; ++r) {
      float z = a0[r] + a1[r] + a2[r] + a3[r] + xpA[r];
      float e = __expf(2.0f * z);
      hv[r] = 1.0f - 2.0f / (e + 1.0f);  // tanh(z)
      hu[r] = f2bf(hv[r]);
    }

    if (t == L_DIM - 1) {
      #pragma unroll
      for (int r = 0; r < 4; ++r)
        out[obase + (size_t)(drow + r) * H_DIM + gcol] = hv[r];
      break;
    }

    const unsigned step = (unsigned)(t + 1);
    const unsigned buf = step & 1;
    u32* sg = slab + (size_t)(buf * 8 + g) * 8192;   // [16][512] u32 stamped
    u32* cp = ctr + (size_t)(buf * 8 + g) * 16;      // 64B-strided counter
    const u32 cbits = step << 16;

    // ---- publish stamped tile (no ack), then bump the counter ----
    #pragma unroll
    for (int r = 0; r < 4; ++r)
      __hip_atomic_store(&sg[(drow + r) * 512 + gcol], cbits | (u32)hu[r],
                         __ATOMIC_RELAXED, __HIP_MEMORY_SCOPE_AGENT);
    __builtin_amdgcn_sched_barrier(0);
    if (lane == 0)
      __hip_atomic_fetch_add(cp, 1u, __ATOMIC_RELAXED, __HIP_MEMORY_SCOPE_AGENT);

    // ---- off-critical-path: out stores + xp pipeline advance ----
    #pragma unroll
    for (int r = 0; r < 4; ++r)
      out[obase + (size_t)(drow + r) * H_DIM + gcol] = hv[r];
    xpA = xpB;
    {
      const int tn = (t + 2 < L_DIM) ? t + 2 : L_DIM - 1;
      const size_t obn = ((size_t)tn * B_DIM + g * 16) * H_DIM;
      #pragma unroll
      for (int r = 0; r < 4; ++r)
        xpB[r] = out[obn + (size_t)(drow + r) * H_DIM + gcol];
    }

    // ---- poll the single arrive-counter (monotonic target) ----
    const u32 target = 32u * ((step + 1) >> 1);
    while (__hip_atomic_load(cp, __ATOMIC_RELAXED, __HIP_MEMORY_SCOPE_AGENT) < target) {}
    __builtin_amdgcn_sched_barrier(0);
    asm volatile("" ::: "memory");

    // ---- pull 128 B/thread (16 u64), stamp-validate, rare retry ----
    const u64* pb = reinterpret_cast<const u64*>(sg) + prow * 256 + pch * 16;
    const u64 M = 0xFFFF0000FFFF0000ull;
    const u64 E = (u64)step * 0x0001000000010000ull;
    u64 pl[16];
    for (;;) {
      #pragma unroll
      for (int j = 0; j < 16; ++j)
        pl[j] = __hip_atomic_load(pb + j, __ATOMIC_RELAXED, __HIP_MEMORY_SCOPE_AGENT);
      u64 b0 = 0, b1 = 0, b2 = 0, b3 = 0;
      #pragma unroll
      for (int j = 0; j < 16; j += 4) {
        b0 |= (pl[j] & M) ^ E;
        b1 |= (pl[j + 1] & M) ^ E;
        b2 |= (pl[j + 2] & M) ^ E;
        b3 |= (pl[j + 3] & M) ^ E;
      }
      if (((b0 | b1) | (b2 | b3)) == 0ull) break;
    }

    // ---- strip stamps, scatter into hb[buf]: 4 aligned b128 writes ----
    #pragma unroll
    for (int q = 0; q < 4; ++q) {
      u16x8 v;
      #pragma unroll
      for (int j = 0; j < 4; ++j) {
        u64 d = pl[q * 4 + j];
        v[2 * j] = (unsigned short)d;
        v[2 * j + 1] = (unsigned short)(d >> 32);
      }
      *reinterpret_cast<u16x8*>(&hb[buf][prow * 520 + pch * 32 + q * 8]) = v;
    }
    __builtin_amdgcn_sched_barrier(0);
    asm volatile("s_waitcnt lgkmcnt(0)" ::: "memory");
    __builtin_amdgcn_sched_barrier(0);
    __builtin_amdgcn_s_barrier();      // hb[buf] = h_{t+1} WG-wide
    __builtin_amdgcn_sched_barrier(0);
  }
}

extern "C" void kernel_launch(void* const* d_in, const int* in_sizes, int n_in,
                              void* d_out, int out_size, void* d_ws, size_t ws_size,
                              hipStream_t stream) {
  (void)in_sizes; (void)n_in; (void)out_size; (void)ws_size;
  const float* x  = (const float*)d_in[0];
  const float* h0 = (const float*)d_in[1];
  const float* Wx = (const float*)d_in[2];
  const float* Wh = (const float*)d_in[3];
  const float* bh = (const float*)d_in[4];
  float* out = (float*)d_out;

  unsigned short* WxHi = (unsigned short*)d_ws;       // 131072 u16 (dead after xproj)
  unsigned short* WxLo = WxHi + 131072;               // 131072 u16 (dead after xproj)
  unsigned short* WhHi = WxLo + 131072;               // 262144 u16
  unsigned short* WhLo = WhHi + 262144;               // 262144 u16 (ends 1572864 B)
  // Stamped exchange slab [2][8][16][512] u32 = 524288 B, aliases WxHi+WxLo
  // exactly; pack_weights rewrites it every launch (stale-stamp destruction).
  u32* slab = (u32*)d_ws;
  u32* ctr  = (u32*)((char*)d_ws + 1572864);          // 16 counters x 64B = 1024 B

  // per-launch: zero arrive-counters (deterministic under graph replay)
  hipMemsetAsync(ctr, 0, 1024, stream);

  hipLaunchKernelGGL(pack_weights, dim3(128), dim3(256), 0, stream,
                     Wx, Wh, WxHi, WxLo, WhHi, WhLo);
  hipLaunchKernelGGL(xproj_kernel, dim3(1024, 4), dim3(256), 0, stream,
                     x, WxHi, WxLo, bh, out);
  hipLaunchKernelGGL(rnn_kernel, dim3(64), dim3(256), 0, stream,
                     h0, WhHi, WhLo, ctr, slab, out);
}

// Round 15
// 2803.745 us; speedup vs baseline: 1.5300x; 1.5300x over previous
//
#include <hip/hip_runtime.h>

#define L_DIM 1024
#define B_DIM 128
#define I_DIM 256
#define H_DIM 512

typedef unsigned short u16x8 __attribute__((ext_vector_type(8)));
typedef __bf16 bf16x8 __attribute__((ext_vector_type(8)));
typedef float f32x4 __attribute__((ext_vector_type(4)));
typedef unsigned long long u64;
typedef unsigned int u32;

static __device__ __forceinline__ unsigned short f2bf(float f) {
  unsigned u = __builtin_bit_cast(unsigned, f);
  u += 0x7FFFu + ((u >> 16) & 1u);
  return (unsigned short)(u >> 16);
}
static __device__ __forceinline__ float bf2f(unsigned short b) {
  return __builtin_bit_cast(float, ((unsigned)b) << 16);
}
static __device__ __forceinline__ bf16x8 ld_frag_g(const unsigned short* p, size_t idx8) {
  return __builtin_bit_cast(bf16x8, reinterpret_cast<const u16x8*>(p)[idx8]);
}

// ---------------------------------------------------------------------------
// Pack Wx and Wh into MFMA B-fragment order, split hi/lo bf16. (unchanged)
// ---------------------------------------------------------------------------
__global__ void pack_weights(const float* __restrict__ Wx, const float* __restrict__ Wh,
                             unsigned short* __restrict__ WxHi, unsigned short* __restrict__ WxLo,
                             unsigned short* __restrict__ WhHi, unsigned short* __restrict__ WhLo) {
  int tid = blockIdx.x * blockDim.x + threadIdx.x;
  if (tid < 32 * 8 * 64) {
    int lane = tid & 63, kt = (tid >> 6) & 7, nt = tid >> 9;
    int n = nt * 16 + (lane & 15), k0 = kt * 32 + (lane >> 4) * 8;
    const float* src = Wx + (size_t)n * I_DIM + k0;
    #pragma unroll
    for (int j = 0; j < 8; ++j) {
      float v = src[j];
      unsigned short hb = f2bf(v);
      WxHi[(size_t)tid * 8 + j] = hb;
      WxLo[(size_t)tid * 8 + j] = f2bf(v - bf2f(hb));
    }
  }
  if (tid < 32 * 16 * 64) {
    int lane = tid & 63, kt = (tid >> 6) & 15, nt = tid >> 10;
    int n = nt * 16 + (lane & 15), k0 = kt * 32 + (lane >> 4) * 8;
    const float* src = Wh + (size_t)n * H_DIM + k0;
    #pragma unroll
    for (int j = 0; j < 8; ++j) {
      float v = src[j];
      unsigned short hb = f2bf(v);
      WhHi[(size_t)tid * 8 + j] = hb;
      WhLo[(size_t)tid * 8 + j] = f2bf(v - bf2f(hb));
    }
  }
}

// ---------------------------------------------------------------------------
// xproj (unchanged)
// ---------------------------------------------------------------------------
__global__ __launch_bounds__(256) void xproj_kernel(const float* __restrict__ x,
    const unsigned short* __restrict__ WxHi, const unsigned short* __restrict__ WxLo,
    const float* __restrict__ bh, float* __restrict__ out) {
  __shared__ unsigned short ahi[128][40];
  __shared__ unsigned short alo[128][40];
  const int tid = threadIdx.x, lane = tid & 63, wid = tid >> 6;
  const int mbase = blockIdx.x * 128, cbase = blockIdx.y * 128;
  const int wrow = (wid >> 1) * 64, wcol = (wid & 1) * 64;
  f32x4 acc[4][4] = {};
  const int srow = tid >> 1, shalf = (tid & 1) * 16;

  for (int kt = 0; kt < 8; ++kt) {
    const f32x4* src = reinterpret_cast<const f32x4*>(
        x + (size_t)(mbase + srow) * I_DIM + kt * 32 + shalf);
    f32x4 v[4];
    v[0] = src[0]; v[1] = src[1]; v[2] = src[2]; v[3] = src[3];
    u16x8 hh[2], ll[2];
    #pragma unroll
    for (int q = 0; q < 2; ++q) {
      #pragma unroll
      for (int e = 0; e < 8; ++e) {
        float f = v[q * 2 + (e >> 2)][e & 3];
        unsigned short hb = f2bf(f);
        hh[q][e] = hb;
        ll[q][e] = f2bf(f - bf2f(hb));
      }
    }
    __syncthreads();
    *reinterpret_cast<u16x8*>(&ahi[srow][shalf]) = hh[0];
    *reinterpret_cast<u16x8*>(&ahi[srow][shalf + 8]) = hh[1];
    *reinterpret_cast<u16x8*>(&alo[srow][shalf]) = ll[0];
    *reinterpret_cast<u16x8*>(&alo[srow][shalf + 8]) = ll[1];
    __syncthreads();

    bf16x8 amh[4], aml[4];
    #pragma unroll
    for (int m = 0; m < 4; ++m) {
      amh[m] = __builtin_bit_cast(bf16x8, *reinterpret_cast<const u16x8*>(
          &ahi[wrow + m * 16 + (lane & 15)][(lane >> 4) * 8]));
      aml[m] = __builtin_bit_cast(bf16x8, *reinterpret_cast<const u16x8*>(
          &alo[wrow + m * 16 + (lane & 15)][(lane >> 4) * 8]));
    }
    bf16x8 bhh[4], bll[4];
    #pragma unroll
    for (int n = 0; n < 4; ++n) {
      int ntg = (cbase + wcol) / 16 + n;
      size_t idx = (size_t)(ntg * 8 + kt) * 64 + lane;
      bhh[n] = ld_frag_g(WxHi, idx);
      bll[n] = ld_frag_g(WxLo, idx);
    }
    #pragma unroll
    for (int m = 0; m < 4; ++m) {
      #pragma unroll
      for (int n = 0; n < 4; ++n) {
        acc[m][n] = __builtin_amdgcn_mfma_f32_16x16x32_bf16(amh[m], bhh[n], acc[m][n], 0, 0, 0);
        acc[m][n] = __builtin_amdgcn_mfma_f32_16x16x32_bf16(aml[m], bhh[n], acc[m][n], 0, 0, 0);
        acc[m][n] = __builtin_amdgcn_mfma_f32_16x16x32_bf16(amh[m], bll[n], acc[m][n], 0, 0, 0);
      }
    }
  }

  #pragma unroll
  for (int n = 0; n < 4; ++n) {
    int col = cbase + wcol + n * 16 + (lane & 15);
    float bv = bh[col];
    #pragma unroll
    for (int m = 0; m < 4; ++m) {
      int rg = mbase + wrow + m * 16 + ((lane >> 4) << 2);
      #pragma unroll
      for (int r = 0; r < 4; ++r)
        out[(size_t)(rg + r) * H_DIM + col] = acc[m][n][r] + bv;
    }
  }
}

// ---------------------------------------------------------------------------
// Recurrence (R4 champion + double-buffered hb + xp depth-2).
// 64 WGs x 256 thr: g = blk&7 (16 batch rows), c = blk>>3 (64 output cols).
// Wave w's Wh fragments in VGPRs/L1. h_t in double-buffered LDS hb[2].
// Exchange (relaxed AGENT atomics only — the proven-live primitive class):
//   producer: 1 packed u64 column-fragment store -> wave-local vmcnt(0)
//             -> per-(WG,wave) tag. Consumer wave w polls EXACTLY the tags
//             of the slots it pulls (source wave == w; race-free, verified),
//             lanes 0..6 poll 7 peer tags, then 7 u64 pulls (slot == tid),
//             scatter into hb[(t+1)&1], lgkmcnt, ONE s_barrier per step.
// Barrier-removal safety: step-t scatter targets hb[(t+1)&1]; all reads of
// that buffer (step t-1 MFMA) precede the end-of-(t-1) barrier (each wave's
// lgkmcnt(0) covers its own reads). xp(t+2) prefetch keeps the poll/pull
// window free of unrelated loads.
// ---------------------------------------------------------------------------
__global__ __launch_bounds__(256, 1) void rnn_kernel(const float* __restrict__ h0,
    const unsigned short* __restrict__ WhHi, const unsigned short* __restrict__ WhLo,
    unsigned int* __restrict__ tags, u64* __restrict__ gbuf,
    float* __restrict__ out) {
  __shared__ unsigned short hb[2][16 * 520];
  const int tid = threadIdx.x, lane = tid & 63, w = tid >> 6;
  const int g = blockIdx.x & 7, c = blockIdx.x >> 3;

  // ---- one-time: Wh fragments -> VGPRs ----
  bf16x8 wfh[16], wfl[16];
  #pragma unroll
  for (int kt = 0; kt < 16; ++kt) {
    size_t idx = (size_t)((c * 4 + w) * 16 + kt) * 64 + lane;
    wfh[kt] = ld_frag_g(WhHi, idx);
    wfl[kt] = ld_frag_g(WhLo, idx);
  }
  // ---- one-time: h0 -> hb[0] bf16 ----
  for (int i = tid; i < 1024; i += 256) {
    int row = i >> 6, col0 = (i & 63) * 8;
    const f32x4* s = reinterpret_cast<const f32x4*>(h0 + (size_t)(g * 16 + row) * H_DIM + col0);
    f32x4 v0 = s[0], v1 = s[1];
    u16x8 hv;
    #pragma unroll
    for (int e = 0; e < 4; ++e) { hv[e] = f2bf(v0[e]); hv[4 + e] = f2bf(v1[e]); }
    *reinterpret_cast<u16x8*>(&hb[0][row * 520 + col0]) = hv;
  }
  __syncthreads();

  const int arow = lane & 15;        // A row (batch) within 16; also D col
  const int aoff = (lane >> 4) * 8;  // A k offset
  const int drow = (lane >> 4) * 4;  // D row base
  const int gcol = c * 64 + w * 16 + (lane & 15);
  // producer slot: (col-within-slice)*4 + row-group
  const int pslot = (w * 16 + (lane & 15)) * 4 + (lane >> 4);
  // consumer decode of slot==tid (its producer wave == own w)
  const int ccol = tid >> 2;
  const int crow0 = (tid & 3) * 4;

  // ---- xp pipeline depth 2: xpA = xp(t), xpB = xp(t+1) in flight ----
  f32x4 xpA, xpB;
  #pragma unroll
  for (int r = 0; r < 4; ++r)
    xpA[r] = out[(size_t)(g * 16 + drow + r) * H_DIM + gcol];
  #pragma unroll
  for (int r = 0; r < 4; ++r)
    xpB[r] = out[(size_t)B_DIM * H_DIM + (size_t)(g * 16 + drow + r) * H_DIM + gcol];

  for (int t = 0; t < L_DIM; ++t) {
    const size_t obase = ((size_t)t * B_DIM + g * 16) * H_DIM;
    const int cur = t & 1;

    // ---- z = h_t . Wh (hi+lo), 32 MFMAs, 4 chains ----
    bf16x8 af[16];
    #pragma unroll
    for (int kt = 0; kt < 16; ++kt)
      af[kt] = __builtin_bit_cast(bf16x8, *reinterpret_cast<const u16x8*>(
          &hb[cur][arow * 520 + kt * 32 + aoff]));
    f32x4 a0 = {}, a1 = {}, a2 = {}, a3 = {};
    #pragma unroll
    for (int kt = 0; kt < 16; kt += 2) {
      a0 = __builtin_amdgcn_mfma_f32_16x16x32_bf16(af[kt], wfh[kt], a0, 0, 0, 0);
      a1 = __builtin_amdgcn_mfma_f32_16x16x32_bf16(af[kt], wfl[kt], a1, 0, 0, 0);
      a2 = __builtin_amdgcn_mfma_f32_16x16x32_bf16(af[kt + 1], wfh[kt + 1], a2, 0, 0, 0);
      a3 = __builtin_amdgcn_mfma_f32_16x16x32_bf16(af[kt + 1], wfl[kt + 1], a3, 0, 0, 0);
    }

    float hv[4]; unsigned short hu[4];
    #pragma unroll
    for (int r = 0; r < 4; ++r) {
      float z = a0[r] + a1[r] + a2[r] + a3[r] + xpA[r];
      float e = __expf(2.0f * z);
      hv[r] = 1.0f - 2.0f / (e + 1.0f);  // tanh(z)
      hu[r] = f2bf(hv[r]);
    }

    if (t == L_DIM - 1) {
      #pragma unroll
      for (int r = 0; r < 4; ++r)
        out[obase + (size_t)(drow + r) * H_DIM + gcol] = hv[r];
      break;
    }

    const unsigned step = (unsigned)(t + 1);
    const unsigned buf = step & 1;

    // ---- publish own column-fragment (1 u64) straight from registers ----
    u64 pv = (u64)hu[0] | ((u64)hu[1] << 16) | ((u64)hu[2] << 32) | ((u64)hu[3] << 48);
    __hip_atomic_store(gbuf + (((size_t)(buf * 8 + g) * 8 + c) * 256 + pslot), pv,
                       __ATOMIC_RELAXED, __HIP_MEMORY_SCOPE_AGENT);
    __builtin_amdgcn_sched_barrier(0);
    asm volatile("s_waitcnt vmcnt(0)" ::: "memory");  // pv at coherent point
    __builtin_amdgcn_sched_barrier(0);
    if (lane == 0)
      __hip_atomic_store(tags + ((size_t)((buf * 8 + g) * 8 + c)) * 4 + w,
                         step, __ATOMIC_RELAXED, __HIP_MEMORY_SCOPE_AGENT);

    // ---- own slice into hb[buf] from registers (no barrier needed:
    //      hb[buf] reads of step t-1 finished before the last barrier) ----
    #pragma unroll
    for (int r = 0; r < 4; ++r)
      hb[buf][(drow + r) * 520 + gcol] = hu[r];

    // ---- off-critical-path: out stores + xp pipeline advance (t+2) ----
    #pragma unroll
    for (int r = 0; r < 4; ++r)
      out[obase + (size_t)(drow + r) * H_DIM + gcol] = hv[r];
    xpA = xpB;
    {
      const int tn = (t + 2 < L_DIM) ? t + 2 : L_DIM - 1;
      const size_t obn = ((size_t)tn * B_DIM + g * 16) * H_DIM;
      #pragma unroll
      for (int r = 0; r < 4; ++r)
        xpB[r] = out[obn + (size_t)(drow + r) * H_DIM + gcol];
    }

    // ---- poll the 7 peer per-wave tags (lanes 0..6); source wave == w ----
    if (lane < 7) {
      int s = lane + (lane >= c ? 1 : 0);
      const unsigned int* tp = tags + ((size_t)((buf * 8 + g) * 8 + s)) * 4 + w;
      while (__hip_atomic_load(tp, __ATOMIC_RELAXED, __HIP_MEMORY_SCOPE_AGENT) < step) {}
    }
    __builtin_amdgcn_sched_barrier(0);
    // ---- issue all 7 pulls (slot == tid; written by source wave w) ----
    u64 pul[7];
    #pragma unroll
    for (int si = 0; si < 7; ++si) {
      int s = si + (si >= c ? 1 : 0);
      pul[si] = __hip_atomic_load(gbuf + (((size_t)(buf * 8 + g) * 8 + s) * 256 + tid),
                                  __ATOMIC_RELAXED, __HIP_MEMORY_SCOPE_AGENT);
    }
    __builtin_amdgcn_sched_barrier(0);
    // ---- scatter peer slices into hb[buf] ----
    #pragma unroll
    for (int si = 0; si < 7; ++si) {
      int s = si + (si >= c ? 1 : 0);
      #pragma unroll
      for (int dr = 0; dr < 4; ++dr)
        hb[buf][(crow0 + dr) * 520 + s * 64 + ccol] = (unsigned short)(pul[si] >> (16 * dr));
    }
    __builtin_amdgcn_sched_barrier(0);
    asm volatile("s_waitcnt lgkmcnt(0)" ::: "memory");
    __builtin_amdgcn_sched_barrier(0);
    __builtin_amdgcn_s_barrier();      // hb[buf] = h_{t+1} WG-wide (1 barrier/step)
    __builtin_amdgcn_sched_barrier(0);
  }
}

extern "C" void kernel_launch(void* const* d_in, const int* in_sizes, int n_in,
                              void* d_out, int out_size, void* d_ws, size_t ws_size,
                              hipStream_t stream) {
  (void)in_sizes; (void)n_in; (void)out_size; (void)ws_size;
  const float* x  = (const float*)d_in[0];
  const float* h0 = (const float*)d_in[1];
  const float* Wx = (const float*)d_in[2];
  const float* Wh = (const float*)d_in[3];
  const float* bh = (const float*)d_in[4];
  float* out = (float*)d_out;

  unsigned short* WxHi = (unsigned short*)d_ws;       // 131072 u16
  unsigned short* WxLo = WxHi + 131072;               // 131072 u16
  unsigned short* WhHi = WxLo + 131072;               // 262144 u16
  unsigned short* WhLo = WhHi + 262144;               // 262144 u16 (ends 1572864 B)
  unsigned int*   tags = (unsigned int*)((char*)d_ws + 1572864);  // 512 u32 = 2 KB
  u64*            gbuf = (u64*)((char*)d_ws + 1575936);           // 32768 u64 = 256 KB

  // per-launch: zero tags (deterministic under graph replay)
  hipMemsetAsync(tags, 0, 2048, stream);

  hipLaunchKernelGGL(pack_weights, dim3(128), dim3(256), 0, stream,
                     Wx, Wh, WxHi, WxLo, WhHi, WhLo);
  hipLaunchKernelGGL(xproj_kernel, dim3(1024, 4), dim3(256), 0, stream,
                     x, WxHi, WxLo, bh, out);
  hipLaunchKernelGGL(rnn_kernel, dim3(64), dim3(256), 0, stream,
                     h0, WhHi, WhLo, tags, gbuf, out);
}